// Round 7
// baseline (353.881 us; speedup 1.0000x reference)
//
#include <hip/hip_runtime.h>
#include <hip/hip_bf16.h>
#include <stdint.h>

#define NN 50000
#define EE 800000
#define BB 512
#define HH 96
#define DIN 5
#define DOUT 192
#define EPSV 1e-5f
#define NBANK 32
#define NB_GATHER 3125          // 3125 * 16 slots = 50000 nodes, 1 node/slot
#define NBLK_SCAN ((NN + 1023) / 1024)
#define PLANE_STRIDE ((size_t)NN * 16)   // u32 words per 32-col plane

__device__ inline float blo(uint32_t w) { return __uint_as_float(w << 16); }
__device__ inline float bhi(uint32_t w) { return __uint_as_float(w & 0xffff0000u); }
__device__ inline uint32_t packbf(float a, float b) {
    uint32_t ua = __float_as_uint(a); ua += 0x7fffu + ((ua >> 16) & 1u);
    uint32_t ub = __float_as_uint(b); ub += 0x7fffu + ((ub >> 16) & 1u);
    return (ua >> 16) | (ub & 0xffff0000u);
}

// ---------------- degree histogram (int) ----------------
__global__ void k_deghist(const int* __restrict__ dst, int* __restrict__ degi) {
    int e = blockIdx.x * blockDim.x + threadIdx.x;
    if (e < EE) atomicAdd(&degi[dst[e]], 1);
}

// ---------------- hierarchical scan, pass 1 ----------------
__global__ __launch_bounds__(1024) void k_scan1(const int* __restrict__ degi,
                                                int* __restrict__ cursor,
                                                int* __restrict__ bsum,
                                                float* __restrict__ dinv) {
    __shared__ int wsum[16], woff[16];
    int i = blockIdx.x * 1024 + threadIdx.x;
    int v = (i < NN) ? degi[i] : 0;
    if (i < NN) dinv[i] = rsqrtf((float)v + 1.0f);
    int lane = threadIdx.x & 63, w = threadIdx.x >> 6;
    int x = v;
#pragma unroll
    for (int o = 1; o < 64; o <<= 1) {
        int y = __shfl_up(x, o, 64);
        if (lane >= o) x += y;
    }
    if (lane == 63) wsum[w] = x;
    __syncthreads();
    if (threadIdx.x == 0) {
        int c = 0;
#pragma unroll
        for (int k = 0; k < 16; ++k) { woff[k] = c; c += wsum[k]; }
        bsum[blockIdx.x] = c;
    }
    __syncthreads();
    if (i < NN) cursor[i] = woff[w] + x - v;
}

// ---------------- scan pass 2: scan block totals; zero stats ----------------
__global__ __launch_bounds__(256) void k_scan2(int* __restrict__ bsum,
                                               int* __restrict__ row_ptr,
                                               float* __restrict__ stats) {
    int t = threadIdx.x;
    for (int i = t; i < 2 * NBANK * 192; i += 256) stats[i] = 0.0f;
    if (t == 0) {
        int c = 0;
        for (int k = 0; k < NBLK_SCAN; ++k) { int s = bsum[k]; bsum[k] = c; c += s; }
        row_ptr[NN] = c;
    }
}

// ---------------- scan pass 3 ----------------
__global__ __launch_bounds__(1024) void k_scan3(const int* __restrict__ bsum,
                                                int* __restrict__ row_ptr,
                                                int* __restrict__ cursor) {
    int i = blockIdx.x * 1024 + threadIdx.x;
    if (i < NN) {
        int rp = cursor[i] + bsum[blockIdx.x];
        row_ptr[i] = rp;
        cursor[i] = rp;
    }
}

// ---------------- CSR fill: col only ----------------
__global__ void k_fill(const int* __restrict__ src, const int* __restrict__ dst,
                       int* __restrict__ cursor, int* __restrict__ col) {
    int e = blockIdx.x * blockDim.x + threadIdx.x;
    if (e >= EE) return;
    int s = src[e], d = dst[e];
    int p = atomicAdd(&cursor[d], 1);
    col[p] = s;
}

// ---- helper: store 12 prescaled bf16 pairs into 3-plane layout ----
__device__ inline void store_planes(uint32_t* __restrict__ hwb, int gr, int q,
                                    const float* acc, float dval) {
    uint32_t wv[12];
#pragma unroll
    for (int p = 0; p < 12; ++p) wv[p] = packbf(acc[2 * p] * dval, acc[2 * p + 1] * dval);
#pragma unroll
    for (int st = 0; st < 3; ++st) {
        int w = 12 * q + 4 * st;
        uint32_t* dstp = hwb + (size_t)(w >> 4) * PLANE_STRIDE + (size_t)gr * 16 + (w & 15);
        *reinterpret_cast<uint4*>(dstp) =
            make_uint4(wv[4 * st], wv[4 * st + 1], wv[4 * st + 2], wv[4 * st + 3]);
    }
}

// ---------------- fused input layer + GEMM1 -> h0 (f32), planes (prescaled bf16) ----------------
__global__ __launch_bounds__(256) void k_gemm_in(const float* __restrict__ x,
                                                 const float* __restrict__ Win,
                                                 const float* __restrict__ bin,
                                                 const float* __restrict__ W1,
                                                 const float* __restrict__ dinv,
                                                 float* __restrict__ h0,
                                                 uint32_t* __restrict__ hwb) {
    __shared__ float sA[64][100];
    __shared__ float sW[96 * 96];
    __shared__ float sWin[5 * 96];
    __shared__ float sbin[96];
    int tid = threadIdx.x;
    int row0 = blockIdx.x * 64;

    for (int i = tid; i < 96 * 96; i += 256) sW[i] = W1[i];
    for (int i = tid; i < 5 * 96; i += 256) sWin[i] = Win[i];
    if (tid < 96) sbin[tid] = bin[tid];
    __syncthreads();

    int r = tid >> 2, q = tid & 3;
    int j0 = q * 24;
    int gr = row0 + r;

    {
        float xv[5];
#pragma unroll
        for (int k = 0; k < DIN; ++k) xv[k] = (gr < NN) ? x[gr * DIN + k] : 0.0f;
        float hv[24];
#pragma unroll
        for (int jj = 0; jj < 24; ++jj) {
            float acc = sbin[j0 + jj];
#pragma unroll
            for (int k = 0; k < DIN; ++k) acc += xv[k] * sWin[k * 96 + j0 + jj];
            hv[jj] = fmaxf(acc, 0.0f);
            sA[r][j0 + jj] = hv[jj];
        }
        if (gr < NN) {
#pragma unroll
            for (int jj = 0; jj < 24; jj += 4)
                *reinterpret_cast<float4*>(&h0[(size_t)gr * 96 + j0 + jj]) =
                    make_float4(hv[jj], hv[jj + 1], hv[jj + 2], hv[jj + 3]);
        }
    }
    __syncthreads();

    float acc[24];
#pragma unroll
    for (int jj = 0; jj < 24; ++jj) acc[jj] = 0.0f;
    for (int k = 0; k < 96; ++k) {
        float a = sA[r][k];
#pragma unroll
        for (int jj = 0; jj < 24; ++jj) acc[jj] += a * sW[k * 96 + j0 + jj];
    }
    if (gr < NN) store_planes(hwb, gr, q, acc, dinv[gr]);
}

// ---------------- gather one 32-col plane (prescaled rows; self-loop + colstats fused) ----
// 16 threads/node; thread t owns word t of the plane row (cols 2t, 2t+1 of this pass)
__global__ __launch_bounds__(256) void k_gatherp(const uint32_t* __restrict__ plane,
                                                 const float* __restrict__ dinv,
                                                 const int* __restrict__ row_ptr,
                                                 const int* __restrict__ col,
                                                 float* __restrict__ agg,
                                                 float* __restrict__ stats,
                                                 int pass) {
    int tid = threadIdx.x;
    int t = tid & 15, slot = tid >> 4;
    int n = blockIdx.x * 16 + slot;   // always < NN

    uint32_t ws = plane[(size_t)n * 16 + t];
    float a0 = blo(ws), a1 = bhi(ws);          // self-loop term (row prescaled by dinv)

    int beg = row_ptr[n], end = row_ptr[n + 1];
    int p = beg;
    for (; p + 3 < end; p += 4) {
        int s0 = col[p], s1 = col[p + 1], s2 = col[p + 2], s3 = col[p + 3];
        uint32_t u0 = plane[(size_t)s0 * 16 + t];
        uint32_t u1 = plane[(size_t)s1 * 16 + t];
        uint32_t u2 = plane[(size_t)s2 * 16 + t];
        uint32_t u3 = plane[(size_t)s3 * 16 + t];
        a0 += blo(u0); a1 += bhi(u0);
        a0 += blo(u1); a1 += bhi(u1);
        a0 += blo(u2); a1 += bhi(u2);
        a0 += blo(u3); a1 += bhi(u3);
    }
    for (; p < end; ++p) {
        uint32_t u = plane[(size_t)col[p] * 16 + t];
        a0 += blo(u); a1 += bhi(u);
    }
    float dn = dinv[n];
    a0 *= dn; a1 *= dn;
    *reinterpret_cast<float2*>(&agg[(size_t)n * 96 + pass * 32 + 2 * t]) = make_float2(a0, a1);

    __shared__ float red[2][32];
    if (tid < 64) reinterpret_cast<float*>(red)[tid] = 0.0f;
    __syncthreads();
    atomicAdd(&red[0][2 * t],     a0);
    atomicAdd(&red[0][2 * t + 1], a1);
    atomicAdd(&red[1][2 * t],     a0 * a0);
    atomicAdd(&red[1][2 * t + 1], a1 * a1);
    __syncthreads();
    float* bank = stats + (blockIdx.x & (NBANK - 1)) * 192;
    if (tid < 32) {
        atomicAdd(&bank[pass * 32 + tid],      red[0][tid]);
        atomicAdd(&bank[96 + pass * 32 + tid], red[1][tid]);
    }
}

// ---------------- fused BN+ReLU+residual + GEMM -> h1 (f32), planes (prescaled bf16) ----------------
__global__ __launch_bounds__(256) void k_gemm_bn(const float* __restrict__ agg,
                                                 const float* __restrict__ hprev,
                                                 const float* __restrict__ stats,
                                                 const float* __restrict__ g,
                                                 const float* __restrict__ be,
                                                 const float* __restrict__ W,
                                                 const float* __restrict__ dinv,
                                                 float* __restrict__ hnew,
                                                 uint32_t* __restrict__ hwb) {
    __shared__ float sA[64][100];
    __shared__ float sW[96 * 96];
    __shared__ float ssc[96], ssh[96];
    int tid = threadIdx.x;
    int row0 = blockIdx.x * 64;

    for (int i = tid; i < 96 * 96; i += 256) sW[i] = W[i];
    if (tid < 96) {
        float s = 0.0f, s2 = 0.0f;
#pragma unroll
        for (int k = 0; k < NBANK; ++k) { s += stats[k * 192 + tid]; s2 += stats[k * 192 + 96 + tid]; }
        float m = s * (1.0f / NN);
        float var = s2 * (1.0f / NN) - m * m;
        float sc = g[tid] * rsqrtf(var + EPSV);
        ssc[tid] = sc;
        ssh[tid] = be[tid] - m * sc;
    }
    __syncthreads();

    for (int i = tid; i < 64 * 24; i += 256) {
        int r = i / 24, qq = i % 24;
        int gr = row0 + r, c = qq * 4;
        float4 v = make_float4(0.0f, 0.0f, 0.0f, 0.0f);
        if (gr < NN) {
            float4 a = *reinterpret_cast<const float4*>(&agg[(size_t)gr * 96 + c]);
            float4 pv = *reinterpret_cast<const float4*>(&hprev[(size_t)gr * 96 + c]);
            v.x = fmaxf(a.x * ssc[c]     + ssh[c],     0.0f) + pv.x;
            v.y = fmaxf(a.y * ssc[c + 1] + ssh[c + 1], 0.0f) + pv.y;
            v.z = fmaxf(a.z * ssc[c + 2] + ssh[c + 2], 0.0f) + pv.z;
            v.w = fmaxf(a.w * ssc[c + 3] + ssh[c + 3], 0.0f) + pv.w;
            *reinterpret_cast<float4*>(&hnew[(size_t)gr * 96 + c]) = v;
        }
        *reinterpret_cast<float4*>(&sA[r][c]) = v;
    }
    __syncthreads();

    int r = tid >> 2, q = tid & 3;
    int j0 = q * 24;
    int gr = row0 + r;
    float acc[24];
#pragma unroll
    for (int jj = 0; jj < 24; ++jj) acc[jj] = 0.0f;
    for (int k = 0; k < 96; ++k) {
        float a = sA[r][k];
#pragma unroll
        for (int jj = 0; jj < 24; ++jj) acc[jj] += a * sW[k * 96 + j0 + jj];
    }
    if (gr < NN) store_planes(hwb, gr, q, acc, dinv[gr]);
}

// ---------------- fused BN2 + pool + GEMM(96x192) + LayerNorm ----------------
__device__ inline int lower_bound_i(const int* __restrict__ a, int n, int v) {
    int lo = 0, hi = n;
    while (lo < hi) { int mid = (lo + hi) >> 1; if (a[mid] < v) lo = mid + 1; else hi = mid; }
    return lo;
}

__global__ __launch_bounds__(192) void k_out(const float* __restrict__ agg,
                                             const float* __restrict__ hprev,
                                             const float* __restrict__ stats,
                                             const float* __restrict__ g,
                                             const float* __restrict__ be,
                                             const int* __restrict__ batch,
                                             const float* __restrict__ Wout,
                                             const float* __restrict__ bout,
                                             const float* __restrict__ lg,
                                             const float* __restrict__ lb,
                                             float* __restrict__ out) {
    __shared__ float ssc[96], ssh[96];
    __shared__ float sp2[2][96];
    __shared__ float sp[96];
    int b = blockIdx.x, t = threadIdx.x;
    if (t < 96) {
        float s = 0.0f, s2 = 0.0f;
#pragma unroll
        for (int k = 0; k < NBANK; ++k) { s += stats[k * 192 + t]; s2 += stats[k * 192 + 96 + t]; }
        float m = s * (1.0f / NN);
        float var = s2 * (1.0f / NN) - m * m;
        float sc = g[t] * rsqrtf(var + EPSV);
        ssc[t] = sc;
        ssh[t] = be[t] - m * sc;
    }
    int lo = lower_bound_i(batch, NN, b);
    int hi = lower_bound_i(batch, NN, b + 1);
    __syncthreads();

    int colc = t % 96, half = t / 96;
    float scc = ssc[colc], shc = ssh[colc];
    float accp = 0.0f;
    for (int r = lo + half; r < hi; r += 2) {
        size_t idx = (size_t)r * 96 + colc;
        accp += fmaxf(agg[idx] * scc + shc, 0.0f) + hprev[idx];
    }
    sp2[half][colc] = accp;
    __syncthreads();
    if (t < 96) {
        float inv = (hi > lo) ? 1.0f / (float)(hi - lo) : 0.0f;
        sp[t] = (sp2[0][t] + sp2[1][t]) * inv;
    }
    __syncthreads();

    float acc = bout[t];
    for (int k = 0; k < 96; ++k) acc += sp[k] * Wout[k * 192 + t];

    __shared__ float svals[192];
    __shared__ float smv[2];
    svals[t] = acc;
    __syncthreads();
    if (t < 64) {
        float a0 = svals[t], a1 = svals[t + 64], a2 = svals[t + 128];
        float s = a0 + a1 + a2;
        float s2 = a0 * a0 + a1 * a1 + a2 * a2;
        for (int o = 32; o > 0; o >>= 1) {
            s += __shfl_down(s, o, 64);
            s2 += __shfl_down(s2, o, 64);
        }
        if (t == 0) { smv[0] = s * (1.0f / 192.0f); smv[1] = s2 * (1.0f / 192.0f); }
    }
    __syncthreads();
    float m = smv[0];
    float var = smv[1] - m * m;
    float rr = rsqrtf(var + EPSV);
    out[b * 192 + t] = lg[t] * (acc - m) * rr + lb[t];
}

extern "C" void kernel_launch(void* const* d_in, const int* in_sizes, int n_in,
                              void* d_out, int out_size, void* d_ws, size_t ws_size,
                              hipStream_t stream) {
    const float* x    = (const float*)d_in[0];
    const int*   ei   = (const int*)  d_in[1];
    const int*   batch= (const int*)  d_in[2];
    const float* Win  = (const float*)d_in[3];
    const float* bin  = (const float*)d_in[4];
    const float* W1   = (const float*)d_in[5];
    const float* g1   = (const float*)d_in[7];
    const float* be1  = (const float*)d_in[8];
    const float* W2   = (const float*)d_in[9];
    const float* g2   = (const float*)d_in[11];
    const float* be2  = (const float*)d_in[12];
    const float* Wout = (const float*)d_in[13];
    const float* bout = (const float*)d_in[14];
    const float* lg   = (const float*)d_in[15];
    const float* lb   = (const float*)d_in[16];
    const int* src = ei;
    const int* dst = ei + EE;

    float*    ws_f   = (float*)d_ws;
    float*    h0     = ws_f;                          // [N,96] f32
    float*    h1     = h0 + (size_t)NN * HH;          // [N,96] f32
    float*    agg    = h1 + (size_t)NN * HH;          // [N,96] f32 (reused both layers)
    float*    dinv   = agg + (size_t)NN * HH;         // [N]
    float*    stats  = dinv + NN;                     // [2 layers][NBANK][192]
    uint32_t* hwb    = (uint32_t*)(stats + 2 * NBANK * 192);  // [3][N][16] prescaled bf16
    int*      degi   = (int*)(hwb + 3 * PLANE_STRIDE);// [N]
    int*      row_ptr= degi + NN;                     // [N+1]
    int*      cursor = row_ptr + NN + 1;              // [N]
    int*      col    = cursor + NN;                   // [E]
    int*      bsum   = col + EE;                      // [NBLK_SCAN]

    const int TB = 256;
    float* stats1 = stats;
    float* stats2 = stats + NBANK * 192;

    // ---- CSR build (dst-grouped; shared by both layers) ----
    hipMemsetAsync(degi, 0, NN * sizeof(int), stream);
    k_deghist<<<(EE + TB - 1) / TB, TB, 0, stream>>>(dst, degi);
    k_scan1<<<NBLK_SCAN, 1024, 0, stream>>>(degi, cursor, bsum, dinv);
    k_scan2<<<1, 256, 0, stream>>>(bsum, row_ptr, stats);
    k_scan3<<<NBLK_SCAN, 1024, 0, stream>>>(bsum, row_ptr, cursor);
    k_fill<<<(EE + TB - 1) / TB, TB, 0, stream>>>(src, dst, cursor, col);

    // ---- layer 0: input MLP + GEMM1 fused ----
    k_gemm_in<<<(NN + 63) / 64, TB, 0, stream>>>(x, Win, bin, W1, dinv, h0, hwb);
    for (int p = 0; p < 3; ++p)
        k_gatherp<<<NB_GATHER, TB, 0, stream>>>(hwb + (size_t)p * PLANE_STRIDE, dinv,
                                                row_ptr, col, agg, stats1, p);

    // ---- layer 1: BN1+res fused into GEMM2 ----
    k_gemm_bn<<<(NN + 63) / 64, TB, 0, stream>>>(agg, h0, stats1, g1, be1, W2, dinv, h1, hwb);
    for (int p = 0; p < 3; ++p)
        k_gatherp<<<NB_GATHER, TB, 0, stream>>>(hwb + (size_t)p * PLANE_STRIDE, dinv,
                                                row_ptr, col, agg, stats2, p);

    // ---- BN2+res fused into pool + readout + layernorm ----
    k_out<<<BB, 192, 0, stream>>>(agg, h1, stats2, g2, be2, batch, Wout, bout, lg, lb,
                                  (float*)d_out);
}